// Round 18
// baseline (455.494 us; speedup 1.0000x reference)
//
#include <hip/hip_runtime.h>
#include <hip/hip_bf16.h>
#include <math.h>

typedef unsigned short u16;
typedef __attribute__((ext_vector_type(8))) short bf16x8;
typedef __attribute__((ext_vector_type(4))) float f32x4;
typedef __attribute__((ext_vector_type(8))) unsigned short u16x8;

#define MFMA16(a, b, c) __builtin_amdgcn_mfma_f32_16x16x32_bf16(a, b, c, 0, 0, 0)
#define SWZ(o) ((o) ^ ((((o) >> 7) & 3) << 4))

__device__ __forceinline__ u16 f2bf(float f) {
  union { float f; unsigned u; } v; v.f = f;
  unsigned r = v.u + 0x7FFFu + ((v.u >> 16) & 1u);
  return (u16)(r >> 16);
}
__device__ __forceinline__ float bf2f(u16 h) {
  union { unsigned u; float f; } v; v.u = ((unsigned)h) << 16;
  return v.f;
}

__device__ __forceinline__ void gload_lds16(const void* g, void* l) {
  __builtin_amdgcn_global_load_lds((__attribute__((address_space(1))) void*)g,
                                   (__attribute__((address_space(3))) void*)l, 16, 0, 0);
}

// ---------------- fused cast fp32 -> bf16 ----------------
__global__ void cast3(const float* __restrict__ a, const float* __restrict__ b,
                      const float* __restrict__ c, u16* __restrict__ oa,
                      u16* __restrict__ ob, u16* __restrict__ oc) {
  int i = blockIdx.x * 256 + threadIdx.x;
  int stride = gridDim.x * 256;
  for (; i < 6291456; i += stride) {
    const float4* src; uint2* dst; int j;
    if (i < 2097152)      { src = (const float4*)a; dst = (uint2*)oa; j = i; }
    else if (i < 5242880) { src = (const float4*)b; dst = (uint2*)ob; j = i - 2097152; }
    else                  { src = (const float4*)c; dst = (uint2*)oc; j = i - 5242880; }
    float4 v = src[j];
    unsigned lo = (unsigned)f2bf(v.x) | ((unsigned)f2bf(v.y) << 16);
    unsigned hi = (unsigned)f2bf(v.z) | ((unsigned)f2bf(v.w) << 16);
    dst[j] = make_uint2(lo, hi);
  }
}

// ---------------- RoPE tables ----------------
__global__ void rope_table(float* __restrict__ tab) {
  int idx = blockIdx.x * 256 + threadIdx.x;   // 131072 total
  int s = idx >> 6, j = idx & 63;
  double ang = (double)s * pow(10000.0, -(double)j / 64.0);
  tab[idx] = (float)cos(ang);
  tab[131072 + idx] = (float)sin(ang);
}

// ======== gemm_r3: C = A[M,K]*Bw[N,K]^T (bf16, K-major), BM=128 BN=256 BK=32 ========
// ring-3 LDS (72KB -> 2 blocks/CU), stage-ahead-2, 1 barrier + counted vmcnt(3)/K-tile,
// 16-MFMA setprio burst, T2 swizzle, 2D XCD chunking.
// EPI 0: fp32 row-major C.
// EPI 1: QKV epilogue — part 0/1 (q,k): RoPE fused; part 2 (v): transposed into vt.
template<int EPI>
__global__ __launch_bounds__(512, 4) void gemm_r3(const u16* __restrict__ A, const u16* __restrict__ Bw,
                                                  void* __restrict__ C, void* __restrict__ C2,
                                                  const float* __restrict__ tab,
                                                  int M, int N, int K,
                                                  int xmBits, int cmMt, int cnNt) {
  __shared__ __align__(16) u16 shmem[36864];     // Al 12288 | Bl 24576 (73728 B)
  u16* Al = shmem;
  u16* Bl = shmem + 12288;
  const int t = threadIdx.x;
  const int w = t >> 6, l = t & 63;
  const int lr = l & 15, lg = l >> 4;
  const int wr = w >> 2, wc = w & 3;
  const int xcd = blockIdx.x & 7;
  const int loc = blockIdx.x >> 3;
  const int xm = xcd & ((1 << xmBits) - 1), xn = xcd >> xmBits;
  const int mt = xm * cmMt + (loc % cmMt);
  const int nt = xn * cnNt + (loc / cmMt);
  const int m0 = mt * 128, n0 = nt * 256;
  const int NT = K >> 5;

  const int pa = t * 16;
  const int oa = SWZ(pa);
  const u16* aSrc = A + (long)(m0 + (oa >> 6)) * K + ((oa & 63) >> 1);
  const int ob0 = SWZ(pa);
  const int ob1 = SWZ(8192 + pa);
  const u16* bSrc0 = Bw + (long)(n0 + (ob0 >> 6)) * K + ((ob0 & 63) >> 1);
  const u16* bSrc1 = Bw + (long)(n0 + ((ob1 - 8192) >> 6) + 128) * K + ((ob1 & 63) >> 1);
  const int ldsWave = w * 512;

  int aro[4], bro[4];
#pragma unroll
  for (int f = 0; f < 4; ++f) {
    int ab = (wr * 64 + f * 16 + lr) * 64 + lg * 16;
    aro[f] = SWZ(ab) >> 1;
    int bb = (wc * 64 + f * 16 + lr) * 64 + lg * 16;
    bro[f] = SWZ(bb) >> 1;
  }

  f32x4 acc[4][4];
#pragma unroll
  for (int i = 0; i < 4; ++i)
#pragma unroll
    for (int j = 0; j < 4; ++j)
#pragma unroll
      for (int e = 0; e < 4; ++e) acc[i][j][e] = 0.f;

#define STAGE(tt, sl)                                                     \
  do {                                                                    \
    gload_lds16(aSrc  + (tt) * 32, Al + (sl) * 4096 + ldsWave);           \
    gload_lds16(bSrc0 + (tt) * 32, Bl + (sl) * 8192 + ldsWave);           \
    gload_lds16(bSrc1 + (tt) * 32, Bl + (sl) * 8192 + 4096 + ldsWave);    \
  } while (0)

  STAGE(0, 0);
  STAGE(1, 1);
  asm volatile("s_waitcnt vmcnt(3)" ::: "memory");
  __builtin_amdgcn_s_barrier();

  int rs = 0, ss = 2;
  for (int tt = 0; tt < NT; ++tt) {
    const u16* as = Al + rs * 4096;
    const u16* bs = Bl + rs * 8192;
    bf16x8 b0 = *(const bf16x8*)(bs + bro[0]);
    bf16x8 b1 = *(const bf16x8*)(bs + bro[1]);
    bf16x8 b2 = *(const bf16x8*)(bs + bro[2]);
    bf16x8 b3 = *(const bf16x8*)(bs + bro[3]);
    bf16x8 a0 = *(const bf16x8*)(as + aro[0]);
    bf16x8 a1 = *(const bf16x8*)(as + aro[1]);
    bf16x8 a2 = *(const bf16x8*)(as + aro[2]);
    bf16x8 a3 = *(const bf16x8*)(as + aro[3]);
    if (tt + 2 < NT) STAGE(tt + 2, ss);
    __builtin_amdgcn_s_setprio(1);
    acc[0][0] = MFMA16(a0, b0, acc[0][0]);
    acc[0][1] = MFMA16(a0, b1, acc[0][1]);
    acc[0][2] = MFMA16(a0, b2, acc[0][2]);
    acc[0][3] = MFMA16(a0, b3, acc[0][3]);
    acc[1][0] = MFMA16(a1, b0, acc[1][0]);
    acc[1][1] = MFMA16(a1, b1, acc[1][1]);
    acc[1][2] = MFMA16(a1, b2, acc[1][2]);
    acc[1][3] = MFMA16(a1, b3, acc[1][3]);
    acc[2][0] = MFMA16(a2, b0, acc[2][0]);
    acc[2][1] = MFMA16(a2, b1, acc[2][1]);
    acc[2][2] = MFMA16(a2, b2, acc[2][2]);
    acc[2][3] = MFMA16(a2, b3, acc[2][3]);
    acc[3][0] = MFMA16(a3, b0, acc[3][0]);
    acc[3][1] = MFMA16(a3, b1, acc[3][1]);
    acc[3][2] = MFMA16(a3, b2, acc[3][2]);
    acc[3][3] = MFMA16(a3, b3, acc[3][3]);
    __builtin_amdgcn_s_setprio(0);
    asm volatile("s_waitcnt lgkmcnt(0)" ::: "memory");
    __builtin_amdgcn_sched_barrier(0);
    if (tt < NT - 2) asm volatile("s_waitcnt vmcnt(3)" ::: "memory");
    else             asm volatile("s_waitcnt vmcnt(0)" ::: "memory");
    __builtin_amdgcn_s_barrier();
    rs = (rs == 2) ? 0 : rs + 1;
    ss = (ss == 2) ? 0 : ss + 1;
  }
#undef STAGE

  if (EPI == 0) {
    float* Co = (float*)C;
#pragma unroll
    for (int mf = 0; mf < 4; ++mf)
#pragma unroll
      for (int nf = 0; nf < 4; ++nf)
#pragma unroll
        for (int j = 0; j < 4; ++j) {
          int row = m0 + wr * 64 + mf * 16 + lg * 4 + j;
          int col = n0 + wc * 64 + nf * 16 + lr;
          Co[(long)row * N + col] = acc[mf][nf][j];
        }
  } else {
    const int part = n0 >> 11;       // uniform per block (tile never crosses 2048)
    if (part < 2) {
      // ---- fused RoPE for q/k: pair exchange via LDS (wave w^1 <=> d^64) ----
#pragma unroll
      for (int mf = 0; mf < 4; ++mf)
#pragma unroll
        for (int nf = 0; nf < 4; ++nf) {
          ushort4 v;
          v.x = f2bf(acc[mf][nf][0]);
          v.y = f2bf(acc[mf][nf][1]);
          v.z = f2bf(acc[mf][nf][2]);
          v.w = f2bf(acc[mf][nf][3]);
          *(ushort4*)&shmem[((((w * 4 + mf) * 4 + nf) * 64) + l) * 4] = v;
        }
      __syncthreads();
      u16* Q = (u16*)C;
      const long PART = 8388608L;    // 2*16*2048*128
      const float scale = (part == 0) ? 0.12751744906275268f : 1.0f;  // 1/sqrt(128)*log2e
      const int dlow = (wc & 1) == 0;
#pragma unroll
      for (int mf = 0; mf < 4; ++mf)
#pragma unroll
        for (int nf = 0; nf < 4; ++nf) {
          ushort4 pv = *(const ushort4*)&shmem[(((((w ^ 1) * 4 + mf) * 4 + nf) * 64) + l) * 4];
#pragma unroll
          for (int j = 0; j < 4; ++j) {
            int row = m0 + wr * 64 + mf * 16 + lg * 4 + j;   // b*2048 + s
            int col = n0 + wc * 64 + nf * 16 + lr;
            int h = (col >> 7) & 15, d = col & 127;
            int b = row >> 11, s = row & 2047;
            int jj = d & 63;
            float cs = tab[s * 64 + jj];
            float sn = tab[131072 + s * 64 + jj];
            float own = acc[mf][nf][j];
            float oth = bf2f(((const u16*)&pv)[j]);
            float o = dlow ? (own * cs - oth * sn) : (own * cs + oth * sn);
            Q[part * PART + ((long)((b * 16 + h) * 2048 + s)) * 128 + d] = f2bf(o * scale);
          }
        }
    } else {
      // ---- v: write transposed into vt[bh][d][s]; j=0..3 are consecutive s ----
      u16* VT = (u16*)C2;
#pragma unroll
      for (int mf = 0; mf < 4; ++mf)
#pragma unroll
        for (int nf = 0; nf < 4; ++nf) {
          int row0 = m0 + wr * 64 + mf * 16 + lg * 4;        // j=0 row
          int col = n0 + wc * 64 + nf * 16 + lr;
          int h = (col >> 7) & 15, d = col & 127;
          int b = row0 >> 11, s0 = row0 & 2047;              // s0 multiple of 4
          ushort4 v;
          v.x = f2bf(acc[mf][nf][0]);
          v.y = f2bf(acc[mf][nf][1]);
          v.z = f2bf(acc[mf][nf][2]);
          v.w = f2bf(acc[mf][nf][3]);
          *(ushort4*)&VT[(long)(b * 16 + h) * 262144 + (long)d * 2048 + s0] = v;
        }
    }
  }
}

// ---------------- Flash attention (causal), QB=KB=64, 4 waves, NO K/V staging ----
// K/V are L2-resident (4 bh per XCD slot = 4MB = one L2): read MFMA fragments
// DIRECTLY from global (R1-validated lane patterns; 64 lanes = 16 full 64B lines
// per load, zero overfetch). No __syncthreads in the loop — Pl is per-wave.
// LDS = Pl only (9KB); VGPR drops (no staging regs) -> up to 4 blocks/CU.
__global__ __launch_bounds__(256, 3) void flash_fwd(const u16* __restrict__ qg, const u16* __restrict__ kg,
                                                    const u16* __restrict__ vtg, u16* __restrict__ ctx) {
  const int bid = blockIdx.x;
  const int xcd = bid & 7;
  const int seq = bid >> 3;
  const int bh = xcd * 4 + (seq & 3);
  const int qi = 31 - (seq >> 2);
  const int t = threadIdx.x, w = t >> 6, l = t & 63;
  const int lr = l & 15, lg = l >> 4;
  const int q0 = qi * 64;
  const int nkv = qi + 1;
  const long skbase = (long)bh * 2048 * 128;
  const long vtbase = (long)bh * 128 * 2048;
  __shared__ __align__(16) u16 Pl[4][16][72];  // per-wave P [q][kv], padded rows

  bf16x8 qf[4];
  {
    const u16* qrow = qg + skbase + (long)(q0 + w * 16 + lr) * 128;
#pragma unroll
    for (int dc = 0; dc < 4; ++dc) qf[dc] = *(const bf16x8*)(qrow + dc * 32 + lg * 8);
  }
  f32x4 acc[8];
#pragma unroll
  for (int dc = 0; dc < 8; ++dc)
#pragma unroll
    for (int e = 0; e < 4; ++e) acc[dc][e] = 0.f;
  float mrow[4] = {-1e30f, -1e30f, -1e30f, -1e30f};
  float lsum[4] = {0.f, 0.f, 0.f, 0.f};

  // direct-fragment bases: K row = kv0 + c*16 + lr, bytes dc*64 + lg*16
  //                        V row (vt) = dc*16 + lr, bytes kv0*2 + kc*64 + lg*16
  const u16* kfb = kg + skbase + (long)lr * 128 + lg * 8;
  const u16* vfb = vtg + vtbase + (long)lr * 2048 + lg * 8;

  for (int kvt = 0; kvt < nkv; ++kvt) {
    const int kv0 = kvt * 64;
    f32x4 sc[4];
#pragma unroll
    for (int c = 0; c < 4; ++c)
#pragma unroll
      for (int e = 0; e < 4; ++e) sc[c][e] = 0.f;

    // QK^T: B-fragments straight from global (L2-hit)
#pragma unroll
    for (int c = 0; c < 4; ++c) {
      const u16* kr = kfb + (long)(kv0 + c * 16) * 128;
      bf16x8 kf0 = *(const bf16x8*)(kr);
      bf16x8 kf1 = *(const bf16x8*)(kr + 32);
      bf16x8 kf2 = *(const bf16x8*)(kr + 64);
      bf16x8 kf3 = *(const bf16x8*)(kr + 96);
      __builtin_amdgcn_s_setprio(1);
      sc[c] = MFMA16(qf[0], kf0, sc[c]);
      sc[c] = MFMA16(qf[1], kf1, sc[c]);
      sc[c] = MFMA16(qf[2], kf2, sc[c]);
      sc[c] = MFMA16(qf[3], kf3, sc[c]);
      __builtin_amdgcn_s_setprio(0);
    }

    if (kvt == qi) {
#pragma unroll
      for (int c = 0; c < 4; ++c)
#pragma unroll
        for (int j = 0; j < 4; ++j) {
          int kvi = kv0 + c * 16 + lr;
          int qq = q0 + w * 16 + lg * 4 + j;
          if (kvi > qq) sc[c][j] = -1e30f;
        }
    }

    float pmax[4];
#pragma unroll
    for (int j = 0; j < 4; ++j)
      pmax[j] = fmaxf(fmaxf(sc[0][j], sc[1][j]), fmaxf(sc[2][j], sc[3][j]));
#pragma unroll
    for (int off = 8; off >= 1; off >>= 1)
#pragma unroll
      for (int j = 0; j < 4; ++j)
        pmax[j] = fmaxf(pmax[j], __shfl_xor(pmax[j], off));

    int skip = __all(pmax[0] <= mrow[0] + 8.f && pmax[1] <= mrow[1] + 8.f &&
                     pmax[2] <= mrow[2] + 8.f && pmax[3] <= mrow[3] + 8.f);
    if (!skip) {
#pragma unroll
      for (int j = 0; j < 4; ++j) {
        float mn = fmaxf(mrow[j], pmax[j]);
        float alpha = __builtin_amdgcn_exp2f(mrow[j] - mn);
        mrow[j] = mn;
        lsum[j] *= alpha;
#pragma unroll
        for (int dc = 0; dc < 8; ++dc) acc[dc][j] *= alpha;
      }
    }

    float rsum[4] = {0.f, 0.f, 0.f, 0.f};
#pragma unroll
    for (int c = 0; c < 4; ++c)
#pragma unroll
      for (int j = 0; j < 4; ++j) {
        float p = __builtin_amdgcn_exp2f(sc[c][j] - mrow[j]);
        sc[c][j] = p;
        rsum[j] += p;
      }
#pragma unroll
    for (int off = 8; off >= 1; off >>= 1)
#pragma unroll
      for (int j = 0; j < 4; ++j)
        rsum[j] += __shfl_xor(rsum[j], off);
#pragma unroll
    for (int j = 0; j < 4; ++j) lsum[j] += rsum[j];

    // P -> per-wave LDS (same-wave write->read; no barrier needed)
#pragma unroll
    for (int c = 0; c < 4; ++c)
#pragma unroll
      for (int j = 0; j < 4; ++j)
        Pl[w][lg * 4 + j][c * 16 + lr] = f2bf(sc[c][j]);

    // PV: V-fragments straight from global vt (L2-hit)
#pragma unroll
    for (int kc = 0; kc < 2; ++kc) {
      bf16x8 pa = *(const bf16x8*)&Pl[w][lr][kc * 32 + lg * 8];
      const u16* vr = vfb + kv0 + kc * 32;
      __builtin_amdgcn_s_setprio(1);
#pragma unroll
      for (int dc = 0; dc < 8; ++dc) {
        bf16x8 vb = *(const bf16x8*)(vr + (long)(dc * 16) * 2048);
        acc[dc] = MFMA16(pa, vb, acc[dc]);
      }
      __builtin_amdgcn_s_setprio(0);
    }
  }

  const int b = bh >> 4, h = bh & 15;
#pragma unroll
  for (int j = 0; j < 4; ++j) {
    float inv = 1.f / lsum[j];
    int s = q0 + w * 16 + lg * 4 + j;
    u16* orow = ctx + ((long)(b * 2048 + s)) * 2048 + h * 128;
#pragma unroll
    for (int dc = 0; dc < 8; ++dc)
      orow[dc * 16 + lr] = f2bf(acc[dc][j] * inv);
  }
}

// ---------------- launch ----------------
extern "C" void kernel_launch(void* const* d_in, const int* in_sizes, int n_in,
                              void* d_out, int out_size, void* d_ws, size_t ws_size,
                              hipStream_t stream) {
  const float* x = (const float*)d_in[0];
  const float* wqkv = (const float*)d_in[1];
  const float* wproj = (const float*)d_in[2];
  float* out = (float*)d_out;

  u16* xb   = (u16*)d_ws;             // 8,388,608 elems
  u16* wqb  = xb + 8388608;           // 12,582,912
  u16* wpb  = wqb + 12582912;         // 4,194,304
  u16* qkv  = wpb + 4194304;          // 25,165,824 (q | k; v slot unused)
  u16* vt   = qkv + 25165824;         // 8,388,608
  u16* ctx  = vt + 8388608;           // 8,388,608
  float* tab = (float*)(ctx + 8388608); // 262,144 floats

  cast3<<<4096, 256, 0, stream>>>(x, wqkv, wproj, xb, wqb, wpb);
  rope_table<<<512, 256, 0, stream>>>(tab);

  // QKV projection + fused RoPE(q,k) + fused V-transpose. 768 blocks; XCD chunk 16x6.
  gemm_r3<1><<<768, 512, 0, stream>>>(xb, wqb, qkv, vt, tab, 4096, 6144, 2048, 1, 16, 6);

  // Flash: QB=64, 1024 blocks, 256 threads, direct-L2 K/V reads (no staging)
  flash_fwd<<<1024, 256, 0, stream>>>(qkv, qkv + 8388608, vt, ctx);

  // Output projection -> fp32 d_out. 256 blocks; XCD chunk 8x4.
  gemm_r3<0><<<256, 512, 0, stream>>>(ctx, wpb, out, nullptr, nullptr, 4096, 2048, 2048, 2, 8, 4);
}

// Round 19
// 271.696 us; speedup vs baseline: 1.6765x; 1.6765x over previous
//
#include <hip/hip_runtime.h>
#include <hip/hip_bf16.h>
#include <math.h>

typedef unsigned short u16;
typedef __attribute__((ext_vector_type(8))) short bf16x8;
typedef __attribute__((ext_vector_type(4))) float f32x4;
typedef __attribute__((ext_vector_type(8))) unsigned short u16x8;

#define MFMA16(a, b, c) __builtin_amdgcn_mfma_f32_16x16x32_bf16(a, b, c, 0, 0, 0)
#define SWZ(o) ((o) ^ ((((o) >> 7) & 3) << 4))

__device__ __forceinline__ u16 f2bf(float f) {
  union { float f; unsigned u; } v; v.f = f;
  unsigned r = v.u + 0x7FFFu + ((v.u >> 16) & 1u);
  return (u16)(r >> 16);
}
__device__ __forceinline__ float bf2f(u16 h) {
  union { unsigned u; float f; } v; v.u = ((unsigned)h) << 16;
  return v.f;
}

__device__ __forceinline__ void gload_lds16(const void* g, void* l) {
  __builtin_amdgcn_global_load_lds((__attribute__((address_space(1))) void*)g,
                                   (__attribute__((address_space(3))) void*)l, 16, 0, 0);
}

// ---------------- fused cast fp32 -> bf16 ----------------
__global__ void cast3(const float* __restrict__ a, const float* __restrict__ b,
                      const float* __restrict__ c, u16* __restrict__ oa,
                      u16* __restrict__ ob, u16* __restrict__ oc) {
  int i = blockIdx.x * 256 + threadIdx.x;
  int stride = gridDim.x * 256;
  for (; i < 6291456; i += stride) {
    const float4* src; uint2* dst; int j;
    if (i < 2097152)      { src = (const float4*)a; dst = (uint2*)oa; j = i; }
    else if (i < 5242880) { src = (const float4*)b; dst = (uint2*)ob; j = i - 2097152; }
    else                  { src = (const float4*)c; dst = (uint2*)oc; j = i - 5242880; }
    float4 v = src[j];
    unsigned lo = (unsigned)f2bf(v.x) | ((unsigned)f2bf(v.y) << 16);
    unsigned hi = (unsigned)f2bf(v.z) | ((unsigned)f2bf(v.w) << 16);
    dst[j] = make_uint2(lo, hi);
  }
}

// ---------------- RoPE tables ----------------
__global__ void rope_table(float* __restrict__ tab) {
  int idx = blockIdx.x * 256 + threadIdx.x;   // 131072 total
  int s = idx >> 6, j = idx & 63;
  double ang = (double)s * pow(10000.0, -(double)j / 64.0);
  tab[idx] = (float)cos(ang);
  tab[131072 + idx] = (float)sin(ang);
}

// ======== gemm_r3: C = A[M,K]*Bw[N,K]^T (bf16, K-major), BM=128 BN=256 BK=32 ========
// ring-3 LDS (72KB -> 2 blocks/CU), stage-ahead-2, 1 barrier + counted vmcnt(3)/K-tile,
// 16-MFMA setprio burst, T2 swizzle, 2D XCD chunking.
// EPI 0: fp32 row-major C.
// EPI 1: QKV epilogue — part 0/1 (q,k): RoPE fused (pair exchange via LDS across
//        wave w^1, cos/sin from tab, q scaled), scatter to qkv [part][b][h][s][d];
//        part 2 (v): write TRANSPOSED into vt[bh][d][s] (C2), 8B stores.
template<int EPI>
__global__ __launch_bounds__(512, 4) void gemm_r3(const u16* __restrict__ A, const u16* __restrict__ Bw,
                                                  void* __restrict__ C, void* __restrict__ C2,
                                                  const float* __restrict__ tab,
                                                  int M, int N, int K,
                                                  int xmBits, int cmMt, int cnNt) {
  __shared__ __align__(16) u16 shmem[36864];     // Al 12288 | Bl 24576 (73728 B)
  u16* Al = shmem;
  u16* Bl = shmem + 12288;
  const int t = threadIdx.x;
  const int w = t >> 6, l = t & 63;
  const int lr = l & 15, lg = l >> 4;
  const int wr = w >> 2, wc = w & 3;
  const int xcd = blockIdx.x & 7;
  const int loc = blockIdx.x >> 3;
  const int xm = xcd & ((1 << xmBits) - 1), xn = xcd >> xmBits;
  const int mt = xm * cmMt + (loc % cmMt);
  const int nt = xn * cnNt + (loc / cmMt);
  const int m0 = mt * 128, n0 = nt * 256;
  const int NT = K >> 5;

  const int pa = t * 16;
  const int oa = SWZ(pa);
  const u16* aSrc = A + (long)(m0 + (oa >> 6)) * K + ((oa & 63) >> 1);
  const int ob0 = SWZ(pa);
  const int ob1 = SWZ(8192 + pa);
  const u16* bSrc0 = Bw + (long)(n0 + (ob0 >> 6)) * K + ((ob0 & 63) >> 1);
  const u16* bSrc1 = Bw + (long)(n0 + ((ob1 - 8192) >> 6) + 128) * K + ((ob1 & 63) >> 1);
  const int ldsWave = w * 512;

  int aro[4], bro[4];
#pragma unroll
  for (int f = 0; f < 4; ++f) {
    int ab = (wr * 64 + f * 16 + lr) * 64 + lg * 16;
    aro[f] = SWZ(ab) >> 1;
    int bb = (wc * 64 + f * 16 + lr) * 64 + lg * 16;
    bro[f] = SWZ(bb) >> 1;
  }

  f32x4 acc[4][4];
#pragma unroll
  for (int i = 0; i < 4; ++i)
#pragma unroll
    for (int j = 0; j < 4; ++j)
#pragma unroll
      for (int e = 0; e < 4; ++e) acc[i][j][e] = 0.f;

#define STAGE(tt, sl)                                                     \
  do {                                                                    \
    gload_lds16(aSrc  + (tt) * 32, Al + (sl) * 4096 + ldsWave);           \
    gload_lds16(bSrc0 + (tt) * 32, Bl + (sl) * 8192 + ldsWave);           \
    gload_lds16(bSrc1 + (tt) * 32, Bl + (sl) * 8192 + 4096 + ldsWave);    \
  } while (0)

  STAGE(0, 0);
  STAGE(1, 1);
  asm volatile("s_waitcnt vmcnt(3)" ::: "memory");
  __builtin_amdgcn_s_barrier();

  int rs = 0, ss = 2;
  for (int tt = 0; tt < NT; ++tt) {
    const u16* as = Al + rs * 4096;
    const u16* bs = Bl + rs * 8192;
    bf16x8 b0 = *(const bf16x8*)(bs + bro[0]);
    bf16x8 b1 = *(const bf16x8*)(bs + bro[1]);
    bf16x8 b2 = *(const bf16x8*)(bs + bro[2]);
    bf16x8 b3 = *(const bf16x8*)(bs + bro[3]);
    bf16x8 a0 = *(const bf16x8*)(as + aro[0]);
    bf16x8 a1 = *(const bf16x8*)(as + aro[1]);
    bf16x8 a2 = *(const bf16x8*)(as + aro[2]);
    bf16x8 a3 = *(const bf16x8*)(as + aro[3]);
    if (tt + 2 < NT) STAGE(tt + 2, ss);
    __builtin_amdgcn_s_setprio(1);
    acc[0][0] = MFMA16(a0, b0, acc[0][0]);
    acc[0][1] = MFMA16(a0, b1, acc[0][1]);
    acc[0][2] = MFMA16(a0, b2, acc[0][2]);
    acc[0][3] = MFMA16(a0, b3, acc[0][3]);
    acc[1][0] = MFMA16(a1, b0, acc[1][0]);
    acc[1][1] = MFMA16(a1, b1, acc[1][1]);
    acc[1][2] = MFMA16(a1, b2, acc[1][2]);
    acc[1][3] = MFMA16(a1, b3, acc[1][3]);
    acc[2][0] = MFMA16(a2, b0, acc[2][0]);
    acc[2][1] = MFMA16(a2, b1, acc[2][1]);
    acc[2][2] = MFMA16(a2, b2, acc[2][2]);
    acc[2][3] = MFMA16(a2, b3, acc[2][3]);
    acc[3][0] = MFMA16(a3, b0, acc[3][0]);
    acc[3][1] = MFMA16(a3, b1, acc[3][1]);
    acc[3][2] = MFMA16(a3, b2, acc[3][2]);
    acc[3][3] = MFMA16(a3, b3, acc[3][3]);
    __builtin_amdgcn_s_setprio(0);
    asm volatile("s_waitcnt lgkmcnt(0)" ::: "memory");
    __builtin_amdgcn_sched_barrier(0);
    if (tt < NT - 2) asm volatile("s_waitcnt vmcnt(3)" ::: "memory");
    else             asm volatile("s_waitcnt vmcnt(0)" ::: "memory");
    __builtin_amdgcn_s_barrier();
    rs = (rs == 2) ? 0 : rs + 1;
    ss = (ss == 2) ? 0 : ss + 1;
  }
#undef STAGE

  if (EPI == 0) {
    float* Co = (float*)C;
#pragma unroll
    for (int mf = 0; mf < 4; ++mf)
#pragma unroll
      for (int nf = 0; nf < 4; ++nf)
#pragma unroll
        for (int j = 0; j < 4; ++j) {
          int row = m0 + wr * 64 + mf * 16 + lg * 4 + j;
          int col = n0 + wc * 64 + nf * 16 + lr;
          Co[(long)row * N + col] = acc[mf][nf][j];
        }
  } else {
    const int part = n0 >> 11;       // uniform per block (tile never crosses 2048)
    if (part < 2) {
      // ---- fused RoPE for q/k: pair exchange via LDS (wave w^1 <=> d^64) ----
#pragma unroll
      for (int mf = 0; mf < 4; ++mf)
#pragma unroll
        for (int nf = 0; nf < 4; ++nf) {
          ushort4 v;
          v.x = f2bf(acc[mf][nf][0]);
          v.y = f2bf(acc[mf][nf][1]);
          v.z = f2bf(acc[mf][nf][2]);
          v.w = f2bf(acc[mf][nf][3]);
          *(ushort4*)&shmem[((((w * 4 + mf) * 4 + nf) * 64) + l) * 4] = v;
        }
      __syncthreads();
      u16* Q = (u16*)C;
      const long PART = 8388608L;    // 2*16*2048*128
      const float scale = (part == 0) ? 0.12751744906275268f : 1.0f;  // 1/sqrt(128)*log2e
      const int dlow = (wc & 1) == 0;
#pragma unroll
      for (int mf = 0; mf < 4; ++mf)
#pragma unroll
        for (int nf = 0; nf < 4; ++nf) {
          ushort4 pv = *(const ushort4*)&shmem[(((((w ^ 1) * 4 + mf) * 4 + nf) * 64) + l) * 4];
#pragma unroll
          for (int j = 0; j < 4; ++j) {
            int row = m0 + wr * 64 + mf * 16 + lg * 4 + j;   // b*2048 + s
            int col = n0 + wc * 64 + nf * 16 + lr;
            int h = (col >> 7) & 15, d = col & 127;
            int b = row >> 11, s = row & 2047;
            int jj = d & 63;
            float cs = tab[s * 64 + jj];
            float sn = tab[131072 + s * 64 + jj];
            float own = acc[mf][nf][j];
            float oth = bf2f(((const u16*)&pv)[j]);
            float o = dlow ? (own * cs - oth * sn) : (own * cs + oth * sn);
            Q[part * PART + ((long)((b * 16 + h) * 2048 + s)) * 128 + d] = f2bf(o * scale);
          }
        }
    } else {
      // ---- v: write transposed into vt[bh][d][s]; j=0..3 are consecutive s ----
      u16* VT = (u16*)C2;
#pragma unroll
      for (int mf = 0; mf < 4; ++mf)
#pragma unroll
        for (int nf = 0; nf < 4; ++nf) {
          int row0 = m0 + wr * 64 + mf * 16 + lg * 4;        // j=0 row
          int col = n0 + wc * 64 + nf * 16 + lr;
          int h = (col >> 7) & 15, d = col & 127;
          int b = row0 >> 11, s0 = row0 & 2047;              // s0 multiple of 4
          ushort4 v;
          v.x = f2bf(acc[mf][nf][0]);
          v.y = f2bf(acc[mf][nf][1]);
          v.z = f2bf(acc[mf][nf][2]);
          v.w = f2bf(acc[mf][nf][3]);
          *(ushort4*)&VT[(long)(b * 16 + h) * 262144 + (long)d * 2048 + s0] = v;
        }
    }
  }
}

// ---------------- Flash attention (causal), QB=KB=64, 4 waves, swizzled K/V LDS ----
// R17-exact (session best, flash ~88us): Kl/Vl linear + XOR involution (both sides),
// Pl padded [4][16][72], prefetch depth 1, bounds (256,3).
// LDS staging is latency-class conversion: cooperative load pays L2 latency once per
// tile per BLOCK (hideable); direct per-fragment global reads pay it per MFMA chain
// (R18: 3.4x regression). Do not remove.
__global__ __launch_bounds__(256, 3) void flash_fwd(const u16* __restrict__ qg, const u16* __restrict__ kg,
                                                    const u16* __restrict__ vtg, u16* __restrict__ ctx) {
  const int bid = blockIdx.x;
  const int xcd = bid & 7;
  const int seq = bid >> 3;
  const int bh = xcd * 4 + (seq & 3);
  const int qi = 31 - (seq >> 2);
  const int t = threadIdx.x, w = t >> 6, l = t & 63;
  const int lr = l & 15, lg = l >> 4;
  const int q0 = qi * 64;
  const int nkv = qi + 1;
  const long skbase = (long)bh * 2048 * 128;
  const long vtbase = (long)bh * 128 * 2048;
  __shared__ __align__(16) u16 Kl[64 * 128];   // 16 KB, swizzled
  __shared__ __align__(16) u16 Vl[128 * 64];   // 16 KB, swizzled
  __shared__ __align__(16) u16 Pl[4][16][72];  // per-wave P [q][kv], padded rows

  bf16x8 qf[4];
  {
    const u16* qrow = qg + skbase + (long)(q0 + w * 16 + lr) * 128;
#pragma unroll
    for (int dc = 0; dc < 4; ++dc) qf[dc] = *(const bf16x8*)(qrow + dc * 32 + lg * 8);
  }
  f32x4 acc[8];
#pragma unroll
  for (int dc = 0; dc < 8; ++dc)
#pragma unroll
    for (int e = 0; e < 4; ++e) acc[dc][e] = 0.f;
  float mrow[4] = {-1e30f, -1e30f, -1e30f, -1e30f};
  float lsum[4] = {0.f, 0.f, 0.f, 0.f};

  const u16* kga = kg + skbase + (long)(t >> 4) * 128 + (t & 15) * 8;
  const u16* vga = vtg + vtbase + (long)(t >> 3) * 2048 + (t & 7) * 8;
  const int kWrO = (t >> 4) * 256 + (((t & 15) * 16) ^ (((t >> 4) & 7) << 4));
  const int vWrO = (t >> 3) * 128 + (((t & 7) * 16) ^ (((t >> 3) & 7) << 4));
  const int msk = (lr & 7) << 4;
  char* KlB = (char*)Kl;
  char* VlB = (char*)Vl;

  u16x8 rk[4], rv[4];
#pragma unroll
  for (int it = 0; it < 4; ++it) {
    rk[it] = *(const u16x8*)(kga + it * 2048);
    rv[it] = *(const u16x8*)(vga + it * 65536);
  }

  for (int kvt = 0; kvt < nkv; ++kvt) {
    __syncthreads();
#pragma unroll
    for (int it = 0; it < 4; ++it) {
      *(u16x8*)(KlB + kWrO + it * 4096) = rk[it];
      *(u16x8*)(VlB + vWrO + it * 4096) = rv[it];
    }
    __syncthreads();
    if (kvt + 1 < nkv) {
      const u16* ka = kga + (long)(kvt + 1) * 8192;
      const u16* va = vga + (long)(kvt + 1) * 64;
#pragma unroll
      for (int it = 0; it < 4; ++it) {
        rk[it] = *(const u16x8*)(ka + it * 2048);
        rv[it] = *(const u16x8*)(va + it * 65536);
      }
    }

    const int kv0 = kvt * 64;
    f32x4 sc[4];
#pragma unroll
    for (int c = 0; c < 4; ++c)
#pragma unroll
      for (int e = 0; e < 4; ++e) sc[c][e] = 0.f;
    __builtin_amdgcn_s_setprio(1);
#pragma unroll
    for (int dc = 0; dc < 4; ++dc)
#pragma unroll
      for (int c = 0; c < 4; ++c) {
        bf16x8 kf = *(const bf16x8*)(KlB + c * 4096 + lr * 256 + ((dc * 64 + lg * 16) ^ msk));
        sc[c] = MFMA16(qf[dc], kf, sc[c]);
      }
    __builtin_amdgcn_s_setprio(0);

    if (kvt == qi) {
#pragma unroll
      for (int c = 0; c < 4; ++c)
#pragma unroll
        for (int j = 0; j < 4; ++j) {
          int kvi = kv0 + c * 16 + lr;
          int qq = q0 + w * 16 + lg * 4 + j;
          if (kvi > qq) sc[c][j] = -1e30f;
        }
    }

    float pmax[4];
#pragma unroll
    for (int j = 0; j < 4; ++j)
      pmax[j] = fmaxf(fmaxf(sc[0][j], sc[1][j]), fmaxf(sc[2][j], sc[3][j]));
#pragma unroll
    for (int off = 8; off >= 1; off >>= 1)
#pragma unroll
      for (int j = 0; j < 4; ++j)
        pmax[j] = fmaxf(pmax[j], __shfl_xor(pmax[j], off));

    int skip = __all(pmax[0] <= mrow[0] + 8.f && pmax[1] <= mrow[1] + 8.f &&
                     pmax[2] <= mrow[2] + 8.f && pmax[3] <= mrow[3] + 8.f);
    if (!skip) {
#pragma unroll
      for (int j = 0; j < 4; ++j) {
        float mn = fmaxf(mrow[j], pmax[j]);
        float alpha = __builtin_amdgcn_exp2f(mrow[j] - mn);
        mrow[j] = mn;
        lsum[j] *= alpha;
#pragma unroll
        for (int dc = 0; dc < 8; ++dc) acc[dc][j] *= alpha;
      }
    }

    float rsum[4] = {0.f, 0.f, 0.f, 0.f};
#pragma unroll
    for (int c = 0; c < 4; ++c)
#pragma unroll
      for (int j = 0; j < 4; ++j) {
        float p = __builtin_amdgcn_exp2f(sc[c][j] - mrow[j]);
        sc[c][j] = p;
        rsum[j] += p;
      }
#pragma unroll
    for (int off = 8; off >= 1; off >>= 1)
#pragma unroll
      for (int j = 0; j < 4; ++j)
        rsum[j] += __shfl_xor(rsum[j], off);
#pragma unroll
    for (int j = 0; j < 4; ++j) lsum[j] += rsum[j];

#pragma unroll
    for (int c = 0; c < 4; ++c)
#pragma unroll
      for (int j = 0; j < 4; ++j)
        Pl[w][lg * 4 + j][c * 16 + lr] = f2bf(sc[c][j]);

    __builtin_amdgcn_s_setprio(1);
#pragma unroll
    for (int kc = 0; kc < 2; ++kc) {
      bf16x8 pa = *(const bf16x8*)&Pl[w][lr][kc * 32 + lg * 8];
#pragma unroll
      for (int dc = 0; dc < 8; ++dc) {
        bf16x8 vb = *(const bf16x8*)(VlB + dc * 2048 + lr * 128 + ((kc * 64 + lg * 16) ^ msk));
        acc[dc] = MFMA16(pa, vb, acc[dc]);
      }
    }
    __builtin_amdgcn_s_setprio(0);
  }

  const int b = bh >> 4, h = bh & 15;
#pragma unroll
  for (int j = 0; j < 4; ++j) {
    float inv = 1.f / lsum[j];
    int s = q0 + w * 16 + lg * 4 + j;
    u16* orow = ctx + ((long)(b * 2048 + s)) * 2048 + h * 128;
#pragma unroll
    for (int dc = 0; dc < 8; ++dc)
      orow[dc * 16 + lr] = f2bf(acc[dc][j] * inv);
  }
}

// ---------------- launch ----------------
extern "C" void kernel_launch(void* const* d_in, const int* in_sizes, int n_in,
                              void* d_out, int out_size, void* d_ws, size_t ws_size,
                              hipStream_t stream) {
  const float* x = (const float*)d_in[0];
  const float* wqkv = (const float*)d_in[1];
  const float* wproj = (const float*)d_in[2];
  float* out = (float*)d_out;

  u16* xb   = (u16*)d_ws;             // 8,388,608 elems
  u16* wqb  = xb + 8388608;           // 12,582,912
  u16* wpb  = wqb + 12582912;         // 4,194,304
  u16* qkv  = wpb + 4194304;          // 25,165,824 (q | k; v slot unused)
  u16* vt   = qkv + 25165824;         // 8,388,608
  u16* ctx  = vt + 8388608;           // 8,388,608
  float* tab = (float*)(ctx + 8388608); // 262,144 floats

  cast3<<<4096, 256, 0, stream>>>(x, wqkv, wproj, xb, wqb, wpb);
  rope_table<<<512, 256, 0, stream>>>(tab);

  // QKV projection + fused RoPE(q,k) + fused V-transpose. 768 blocks; XCD chunk 16x6.
  gemm_r3<1><<<768, 512, 0, stream>>>(xb, wqb, qkv, vt, tab, 4096, 6144, 2048, 1, 16, 6);

  // Flash: QB=64, 1024 blocks, 256 threads, swizzled K/V LDS (R17-exact)
  flash_fwd<<<1024, 256, 0, stream>>>(qkv, qkv + 8388608, vt, ctx);

  // Output projection -> fp32 d_out. 256 blocks; XCD chunk 8x4.
  gemm_r3<0><<<256, 512, 0, stream>>>(ctx, wpb, out, nullptr, nullptr, 4096, 2048, 2048, 2, 8, 4);
}

// Round 20
// 264.792 us; speedup vs baseline: 1.7202x; 1.0261x over previous
//
#include <hip/hip_runtime.h>
#include <hip/hip_bf16.h>
#include <math.h>

typedef unsigned short u16;
typedef __attribute__((ext_vector_type(8))) short bf16x8;
typedef __attribute__((ext_vector_type(4))) float f32x4;
typedef __attribute__((ext_vector_type(8))) unsigned short u16x8;

#define MFMA16(a, b, c) __builtin_amdgcn_mfma_f32_16x16x32_bf16(a, b, c, 0, 0, 0)
#define SWZ(o) ((o) ^ ((((o) >> 7) & 3) << 4))

__device__ __forceinline__ u16 f2bf(float f) {
  union { float f; unsigned u; } v; v.f = f;
  unsigned r = v.u + 0x7FFFu + ((v.u >> 16) & 1u);
  return (u16)(r >> 16);
}
__device__ __forceinline__ float bf2f(u16 h) {
  union { unsigned u; float f; } v; v.u = ((unsigned)h) << 16;
  return v.f;
}

__device__ __forceinline__ void gload_lds16(const void* g, void* l) {
  __builtin_amdgcn_global_load_lds((__attribute__((address_space(1))) void*)g,
                                   (__attribute__((address_space(3))) void*)l, 16, 0, 0);
}

// ---------------- fused cast fp32 -> bf16 ----------------
__global__ void cast3(const float* __restrict__ a, const float* __restrict__ b,
                      const float* __restrict__ c, u16* __restrict__ oa,
                      u16* __restrict__ ob, u16* __restrict__ oc) {
  int i = blockIdx.x * 256 + threadIdx.x;
  int stride = gridDim.x * 256;
  for (; i < 6291456; i += stride) {
    const float4* src; uint2* dst; int j;
    if (i < 2097152)      { src = (const float4*)a; dst = (uint2*)oa; j = i; }
    else if (i < 5242880) { src = (const float4*)b; dst = (uint2*)ob; j = i - 2097152; }
    else                  { src = (const float4*)c; dst = (uint2*)oc; j = i - 5242880; }
    float4 v = src[j];
    unsigned lo = (unsigned)f2bf(v.x) | ((unsigned)f2bf(v.y) << 16);
    unsigned hi = (unsigned)f2bf(v.z) | ((unsigned)f2bf(v.w) << 16);
    dst[j] = make_uint2(lo, hi);
  }
}

// ---------------- RoPE tables ----------------
__global__ void rope_table(float* __restrict__ tab) {
  int idx = blockIdx.x * 256 + threadIdx.x;   // 131072 total
  int s = idx >> 6, j = idx & 63;
  double ang = (double)s * pow(10000.0, -(double)j / 64.0);
  tab[idx] = (float)cos(ang);
  tab[131072 + idx] = (float)sin(ang);
}

// ======== gemm_r3: C = A[M,K]*Bw[N,K]^T (bf16, K-major), BM=128 BN=256 BK=32 ========
// ring-3 LDS (72KB -> 2 blocks/CU), stage-ahead-2, 1 barrier + counted vmcnt(3)/K-tile,
// 16-MFMA setprio burst, T2 swizzle, 2D XCD chunking.
// EPI 0: fp32 row-major C.
// EPI 1: QKV epilogue — part 0/1 (q,k): RoPE fused (pair exchange via LDS across
//        wave w^1, cos/sin from tab, q scaled), scatter to qkv [part][b][h][s][d];
//        part 2 (v): write TRANSPOSED into vt[bh][d][s] (C2), 8B stores.
template<int EPI>
__global__ __launch_bounds__(512, 4) void gemm_r3(const u16* __restrict__ A, const u16* __restrict__ Bw,
                                                  void* __restrict__ C, void* __restrict__ C2,
                                                  const float* __restrict__ tab,
                                                  int M, int N, int K,
                                                  int xmBits, int cmMt, int cnNt) {
  __shared__ __align__(16) u16 shmem[36864];     // Al 12288 | Bl 24576 (73728 B)
  u16* Al = shmem;
  u16* Bl = shmem + 12288;
  const int t = threadIdx.x;
  const int w = t >> 6, l = t & 63;
  const int lr = l & 15, lg = l >> 4;
  const int wr = w >> 2, wc = w & 3;
  const int xcd = blockIdx.x & 7;
  const int loc = blockIdx.x >> 3;
  const int xm = xcd & ((1 << xmBits) - 1), xn = xcd >> xmBits;
  const int mt = xm * cmMt + (loc % cmMt);
  const int nt = xn * cnNt + (loc / cmMt);
  const int m0 = mt * 128, n0 = nt * 256;
  const int NT = K >> 5;

  const int pa = t * 16;
  const int oa = SWZ(pa);
  const u16* aSrc = A + (long)(m0 + (oa >> 6)) * K + ((oa & 63) >> 1);
  const int ob0 = SWZ(pa);
  const int ob1 = SWZ(8192 + pa);
  const u16* bSrc0 = Bw + (long)(n0 + (ob0 >> 6)) * K + ((ob0 & 63) >> 1);
  const u16* bSrc1 = Bw + (long)(n0 + ((ob1 - 8192) >> 6) + 128) * K + ((ob1 & 63) >> 1);
  const int ldsWave = w * 512;

  int aro[4], bro[4];
#pragma unroll
  for (int f = 0; f < 4; ++f) {
    int ab = (wr * 64 + f * 16 + lr) * 64 + lg * 16;
    aro[f] = SWZ(ab) >> 1;
    int bb = (wc * 64 + f * 16 + lr) * 64 + lg * 16;
    bro[f] = SWZ(bb) >> 1;
  }

  f32x4 acc[4][4];
#pragma unroll
  for (int i = 0; i < 4; ++i)
#pragma unroll
    for (int j = 0; j < 4; ++j)
#pragma unroll
      for (int e = 0; e < 4; ++e) acc[i][j][e] = 0.f;

#define STAGE(tt, sl)                                                     \
  do {                                                                    \
    gload_lds16(aSrc  + (tt) * 32, Al + (sl) * 4096 + ldsWave);           \
    gload_lds16(bSrc0 + (tt) * 32, Bl + (sl) * 8192 + ldsWave);           \
    gload_lds16(bSrc1 + (tt) * 32, Bl + (sl) * 8192 + 4096 + ldsWave);    \
  } while (0)

  STAGE(0, 0);
  STAGE(1, 1);
  asm volatile("s_waitcnt vmcnt(3)" ::: "memory");
  __builtin_amdgcn_s_barrier();

  int rs = 0, ss = 2;
  for (int tt = 0; tt < NT; ++tt) {
    const u16* as = Al + rs * 4096;
    const u16* bs = Bl + rs * 8192;
    bf16x8 b0 = *(const bf16x8*)(bs + bro[0]);
    bf16x8 b1 = *(const bf16x8*)(bs + bro[1]);
    bf16x8 b2 = *(const bf16x8*)(bs + bro[2]);
    bf16x8 b3 = *(const bf16x8*)(bs + bro[3]);
    bf16x8 a0 = *(const bf16x8*)(as + aro[0]);
    bf16x8 a1 = *(const bf16x8*)(as + aro[1]);
    bf16x8 a2 = *(const bf16x8*)(as + aro[2]);
    bf16x8 a3 = *(const bf16x8*)(as + aro[3]);
    if (tt + 2 < NT) STAGE(tt + 2, ss);
    __builtin_amdgcn_s_setprio(1);
    acc[0][0] = MFMA16(a0, b0, acc[0][0]);
    acc[0][1] = MFMA16(a0, b1, acc[0][1]);
    acc[0][2] = MFMA16(a0, b2, acc[0][2]);
    acc[0][3] = MFMA16(a0, b3, acc[0][3]);
    acc[1][0] = MFMA16(a1, b0, acc[1][0]);
    acc[1][1] = MFMA16(a1, b1, acc[1][1]);
    acc[1][2] = MFMA16(a1, b2, acc[1][2]);
    acc[1][3] = MFMA16(a1, b3, acc[1][3]);
    acc[2][0] = MFMA16(a2, b0, acc[2][0]);
    acc[2][1] = MFMA16(a2, b1, acc[2][1]);
    acc[2][2] = MFMA16(a2, b2, acc[2][2]);
    acc[2][3] = MFMA16(a2, b3, acc[2][3]);
    acc[3][0] = MFMA16(a3, b0, acc[3][0]);
    acc[3][1] = MFMA16(a3, b1, acc[3][1]);
    acc[3][2] = MFMA16(a3, b2, acc[3][2]);
    acc[3][3] = MFMA16(a3, b3, acc[3][3]);
    __builtin_amdgcn_s_setprio(0);
    asm volatile("s_waitcnt lgkmcnt(0)" ::: "memory");
    __builtin_amdgcn_sched_barrier(0);
    if (tt < NT - 2) asm volatile("s_waitcnt vmcnt(3)" ::: "memory");
    else             asm volatile("s_waitcnt vmcnt(0)" ::: "memory");
    __builtin_amdgcn_s_barrier();
    rs = (rs == 2) ? 0 : rs + 1;
    ss = (ss == 2) ? 0 : ss + 1;
  }
#undef STAGE

  if (EPI == 0) {
    float* Co = (float*)C;
#pragma unroll
    for (int mf = 0; mf < 4; ++mf)
#pragma unroll
      for (int nf = 0; nf < 4; ++nf)
#pragma unroll
        for (int j = 0; j < 4; ++j) {
          int row = m0 + wr * 64 + mf * 16 + lg * 4 + j;
          int col = n0 + wc * 64 + nf * 16 + lr;
          Co[(long)row * N + col] = acc[mf][nf][j];
        }
  } else {
    const int part = n0 >> 11;       // uniform per block (tile never crosses 2048)
    if (part < 2) {
      // ---- fused RoPE for q/k: pair exchange via LDS (wave w^1 <=> d^64) ----
#pragma unroll
      for (int mf = 0; mf < 4; ++mf)
#pragma unroll
        for (int nf = 0; nf < 4; ++nf) {
          ushort4 v;
          v.x = f2bf(acc[mf][nf][0]);
          v.y = f2bf(acc[mf][nf][1]);
          v.z = f2bf(acc[mf][nf][2]);
          v.w = f2bf(acc[mf][nf][3]);
          *(ushort4*)&shmem[((((w * 4 + mf) * 4 + nf) * 64) + l) * 4] = v;
        }
      __syncthreads();
      u16* Q = (u16*)C;
      const long PART = 8388608L;    // 2*16*2048*128
      const float scale = (part == 0) ? 0.12751744906275268f : 1.0f;  // 1/sqrt(128)*log2e
      const int dlow = (wc & 1) == 0;
#pragma unroll
      for (int mf = 0; mf < 4; ++mf)
#pragma unroll
        for (int nf = 0; nf < 4; ++nf) {
          ushort4 pv = *(const ushort4*)&shmem[(((((w ^ 1) * 4 + mf) * 4 + nf) * 64) + l) * 4];
#pragma unroll
          for (int j = 0; j < 4; ++j) {
            int row = m0 + wr * 64 + mf * 16 + lg * 4 + j;   // b*2048 + s
            int col = n0 + wc * 64 + nf * 16 + lr;
            int h = (col >> 7) & 15, d = col & 127;
            int b = row >> 11, s = row & 2047;
            int jj = d & 63;
            float cs = tab[s * 64 + jj];
            float sn = tab[131072 + s * 64 + jj];
            float own = acc[mf][nf][j];
            float oth = bf2f(((const u16*)&pv)[j]);
            float o = dlow ? (own * cs - oth * sn) : (own * cs + oth * sn);
            Q[part * PART + ((long)((b * 16 + h) * 2048 + s)) * 128 + d] = f2bf(o * scale);
          }
        }
    } else {
      // ---- v: write transposed into vt[bh][d][s]; j=0..3 are consecutive s ----
      u16* VT = (u16*)C2;
#pragma unroll
      for (int mf = 0; mf < 4; ++mf)
#pragma unroll
        for (int nf = 0; nf < 4; ++nf) {
          int row0 = m0 + wr * 64 + mf * 16 + lg * 4;        // j=0 row
          int col = n0 + wc * 64 + nf * 16 + lr;
          int h = (col >> 7) & 15, d = col & 127;
          int b = row0 >> 11, s0 = row0 & 2047;              // s0 multiple of 4
          ushort4 v;
          v.x = f2bf(acc[mf][nf][0]);
          v.y = f2bf(acc[mf][nf][1]);
          v.z = f2bf(acc[mf][nf][2]);
          v.w = f2bf(acc[mf][nf][3]);
          *(ushort4*)&VT[(long)(b * 16 + h) * 262144 + (long)d * 2048 + s0] = v;
        }
    }
  }
}

// ---------------- Flash attention (causal), QB=KB=64, 4 waves, swizzled K/V LDS ----
// R17 structure with ONE algebraic change: the per-step cross-lane SUM reduce is
// removed (lsum stays lane-partial; alpha is uniform across the 16-lane group since
// pmax IS reduced, so partials rescale identically). One shfl_xor tree after the
// kv-loop recovers the exact row sum. Saves 16 shfl + 16 adds per step.
__global__ __launch_bounds__(256, 3) void flash_fwd(const u16* __restrict__ qg, const u16* __restrict__ kg,
                                                    const u16* __restrict__ vtg, u16* __restrict__ ctx) {
  const int bid = blockIdx.x;
  const int xcd = bid & 7;
  const int seq = bid >> 3;
  const int bh = xcd * 4 + (seq & 3);
  const int qi = 31 - (seq >> 2);
  const int t = threadIdx.x, w = t >> 6, l = t & 63;
  const int lr = l & 15, lg = l >> 4;
  const int q0 = qi * 64;
  const int nkv = qi + 1;
  const long skbase = (long)bh * 2048 * 128;
  const long vtbase = (long)bh * 128 * 2048;
  __shared__ __align__(16) u16 Kl[64 * 128];   // 16 KB, swizzled
  __shared__ __align__(16) u16 Vl[128 * 64];   // 16 KB, swizzled
  __shared__ __align__(16) u16 Pl[4][16][72];  // per-wave P [q][kv], padded rows

  bf16x8 qf[4];
  {
    const u16* qrow = qg + skbase + (long)(q0 + w * 16 + lr) * 128;
#pragma unroll
    for (int dc = 0; dc < 4; ++dc) qf[dc] = *(const bf16x8*)(qrow + dc * 32 + lg * 8);
  }
  f32x4 acc[8];
#pragma unroll
  for (int dc = 0; dc < 8; ++dc)
#pragma unroll
    for (int e = 0; e < 4; ++e) acc[dc][e] = 0.f;
  float mrow[4] = {-1e30f, -1e30f, -1e30f, -1e30f};
  float lsum[4] = {0.f, 0.f, 0.f, 0.f};        // LANE-PARTIAL row sums

  const u16* kga = kg + skbase + (long)(t >> 4) * 128 + (t & 15) * 8;
  const u16* vga = vtg + vtbase + (long)(t >> 3) * 2048 + (t & 7) * 8;
  const int kWrO = (t >> 4) * 256 + (((t & 15) * 16) ^ (((t >> 4) & 7) << 4));
  const int vWrO = (t >> 3) * 128 + (((t & 7) * 16) ^ (((t >> 3) & 7) << 4));
  const int msk = (lr & 7) << 4;
  char* KlB = (char*)Kl;
  char* VlB = (char*)Vl;

  u16x8 rk[4], rv[4];
#pragma unroll
  for (int it = 0; it < 4; ++it) {
    rk[it] = *(const u16x8*)(kga + it * 2048);
    rv[it] = *(const u16x8*)(vga + it * 65536);
  }

  for (int kvt = 0; kvt < nkv; ++kvt) {
    __syncthreads();
#pragma unroll
    for (int it = 0; it < 4; ++it) {
      *(u16x8*)(KlB + kWrO + it * 4096) = rk[it];
      *(u16x8*)(VlB + vWrO + it * 4096) = rv[it];
    }
    __syncthreads();
    if (kvt + 1 < nkv) {
      const u16* ka = kga + (long)(kvt + 1) * 8192;
      const u16* va = vga + (long)(kvt + 1) * 64;
#pragma unroll
      for (int it = 0; it < 4; ++it) {
        rk[it] = *(const u16x8*)(ka + it * 2048);
        rv[it] = *(const u16x8*)(va + it * 65536);
      }
    }

    const int kv0 = kvt * 64;
    f32x4 sc[4];
#pragma unroll
    for (int c = 0; c < 4; ++c)
#pragma unroll
      for (int e = 0; e < 4; ++e) sc[c][e] = 0.f;
    __builtin_amdgcn_s_setprio(1);
#pragma unroll
    for (int dc = 0; dc < 4; ++dc)
#pragma unroll
      for (int c = 0; c < 4; ++c) {
        bf16x8 kf = *(const bf16x8*)(KlB + c * 4096 + lr * 256 + ((dc * 64 + lg * 16) ^ msk));
        sc[c] = MFMA16(qf[dc], kf, sc[c]);
      }
    __builtin_amdgcn_s_setprio(0);

    if (kvt == qi) {
#pragma unroll
      for (int c = 0; c < 4; ++c)
#pragma unroll
        for (int j = 0; j < 4; ++j) {
          int kvi = kv0 + c * 16 + lr;
          int qq = q0 + w * 16 + lg * 4 + j;
          if (kvi > qq) sc[c][j] = -1e30f;
        }
    }

    float pmax[4];
#pragma unroll
    for (int j = 0; j < 4; ++j)
      pmax[j] = fmaxf(fmaxf(sc[0][j], sc[1][j]), fmaxf(sc[2][j], sc[3][j]));
#pragma unroll
    for (int off = 8; off >= 1; off >>= 1)
#pragma unroll
      for (int j = 0; j < 4; ++j)
        pmax[j] = fmaxf(pmax[j], __shfl_xor(pmax[j], off));

    int skip = __all(pmax[0] <= mrow[0] + 8.f && pmax[1] <= mrow[1] + 8.f &&
                     pmax[2] <= mrow[2] + 8.f && pmax[3] <= mrow[3] + 8.f);
    if (!skip) {
      // alpha is uniform across the 16-lane group (pmax reduced) -> lane-partial
      // lsum rescales consistently.
#pragma unroll
      for (int j = 0; j < 4; ++j) {
        float mn = fmaxf(mrow[j], pmax[j]);
        float alpha = __builtin_amdgcn_exp2f(mrow[j] - mn);
        mrow[j] = mn;
        lsum[j] *= alpha;
#pragma unroll
        for (int dc = 0; dc < 8; ++dc) acc[dc][j] *= alpha;
      }
    }

#pragma unroll
    for (int c = 0; c < 4; ++c)
#pragma unroll
      for (int j = 0; j < 4; ++j) {
        float p = __builtin_amdgcn_exp2f(sc[c][j] - mrow[j]);
        sc[c][j] = p;
        lsum[j] += p;                 // lane-partial; no per-step shfl reduce
      }

#pragma unroll
    for (int c = 0; c < 4; ++c)
#pragma unroll
      for (int j = 0; j < 4; ++j)
        Pl[w][lg * 4 + j][c * 16 + lr] = f2bf(sc[c][j]);

    __builtin_amdgcn_s_setprio(1);
#pragma unroll
    for (int kc = 0; kc < 2; ++kc) {
      bf16x8 pa = *(const bf16x8*)&Pl[w][lr][kc * 32 + lg * 8];
#pragma unroll
      for (int dc = 0; dc < 8; ++dc) {
        bf16x8 vb = *(const bf16x8*)(VlB + dc * 2048 + lr * 128 + ((kc * 64 + lg * 16) ^ msk));
        acc[dc] = MFMA16(pa, vb, acc[dc]);
      }
    }
    __builtin_amdgcn_s_setprio(0);
  }

  // final cross-lane sum reduce (once, instead of per step)
#pragma unroll
  for (int off = 8; off >= 1; off >>= 1)
#pragma unroll
    for (int j = 0; j < 4; ++j)
      lsum[j] += __shfl_xor(lsum[j], off);

  const int b = bh >> 4, h = bh & 15;
#pragma unroll
  for (int j = 0; j < 4; ++j) {
    float inv = 1.f / lsum[j];
    int s = q0 + w * 16 + lg * 4 + j;
    u16* orow = ctx + ((long)(b * 2048 + s)) * 2048 + h * 128;
#pragma unroll
    for (int dc = 0; dc < 8; ++dc)
      orow[dc * 16 + lr] = f2bf(acc[dc][j] * inv);
  }
}

// ---------------- launch ----------------
extern "C" void kernel_launch(void* const* d_in, const int* in_sizes, int n_in,
                              void* d_out, int out_size, void* d_ws, size_t ws_size,
                              hipStream_t stream) {
  const float* x = (const float*)d_in[0];
  const float* wqkv = (const float*)d_in[1];
  const float* wproj = (const float*)d_in[2];
  float* out = (float*)d_out;

  u16* xb   = (u16*)d_ws;             // 8,388,608 elems
  u16* wqb  = xb + 8388608;           // 12,582,912
  u16* wpb  = wqb + 12582912;         // 4,194,304
  u16* qkv  = wpb + 4194304;          // 25,165,824 (q | k; v slot unused)
  u16* vt   = qkv + 25165824;         // 8,388,608
  u16* ctx  = vt + 8388608;           // 8,388,608
  float* tab = (float*)(ctx + 8388608); // 262,144 floats

  cast3<<<4096, 256, 0, stream>>>(x, wqkv, wproj, xb, wqb, wpb);
  rope_table<<<512, 256, 0, stream>>>(tab);

  // QKV projection + fused RoPE(q,k) + fused V-transpose. 768 blocks; XCD chunk 16x6.
  gemm_r3<1><<<768, 512, 0, stream>>>(xb, wqb, qkv, vt, tab, 4096, 6144, 2048, 1, 16, 6);

  // Flash: QB=64, 1024 blocks, 256 threads, deferred sum-reduce
  flash_fwd<<<1024, 256, 0, stream>>>(qkv, qkv + 8388608, vt, ctx);

  // Output projection -> fp32 d_out. 256 blocks; XCD chunk 8x4.
  gemm_r3<0><<<256, 512, 0, stream>>>(ctx, wpb, out, nullptr, nullptr, 4096, 2048, 2048, 2, 8, 4);
}

// Round 21
// 241.602 us; speedup vs baseline: 1.8853x; 1.0960x over previous
//
#include <hip/hip_runtime.h>
#include <hip/hip_bf16.h>
#include <math.h>

typedef unsigned short u16;
typedef __attribute__((ext_vector_type(8))) short bf16x8;
typedef __attribute__((ext_vector_type(4))) float f32x4;
typedef __attribute__((ext_vector_type(8))) unsigned short u16x8;

#define MFMA16(a, b, c) __builtin_amdgcn_mfma_f32_16x16x32_bf16(a, b, c, 0, 0, 0)
#define SWZ(o) ((o) ^ ((((o) >> 7) & 3) << 4))

__device__ __forceinline__ u16 f2bf(float f) {
  union { float f; unsigned u; } v; v.f = f;
  unsigned r = v.u + 0x7FFFu + ((v.u >> 16) & 1u);
  return (u16)(r >> 16);
}
__device__ __forceinline__ float bf2f(u16 h) {
  union { unsigned u; float f; } v; v.u = ((unsigned)h) << 16;
  return v.f;
}

__device__ __forceinline__ void gload_lds16(const void* g, void* l) {
  __builtin_amdgcn_global_load_lds((__attribute__((address_space(1))) void*)g,
                                   (__attribute__((address_space(3))) void*)l, 16, 0, 0);
}

// ---------------- fused cast fp32 -> bf16 ----------------
__global__ void cast3(const float* __restrict__ a, const float* __restrict__ b,
                      const float* __restrict__ c, u16* __restrict__ oa,
                      u16* __restrict__ ob, u16* __restrict__ oc) {
  int i = blockIdx.x * 256 + threadIdx.x;
  int stride = gridDim.x * 256;
  for (; i < 6291456; i += stride) {
    const float4* src; uint2* dst; int j;
    if (i < 2097152)      { src = (const float4*)a; dst = (uint2*)oa; j = i; }
    else if (i < 5242880) { src = (const float4*)b; dst = (uint2*)ob; j = i - 2097152; }
    else                  { src = (const float4*)c; dst = (uint2*)oc; j = i - 5242880; }
    float4 v = src[j];
    unsigned lo = (unsigned)f2bf(v.x) | ((unsigned)f2bf(v.y) << 16);
    unsigned hi = (unsigned)f2bf(v.z) | ((unsigned)f2bf(v.w) << 16);
    dst[j] = make_uint2(lo, hi);
  }
}

// ---------------- RoPE tables ----------------
__global__ void rope_table(float* __restrict__ tab) {
  int idx = blockIdx.x * 256 + threadIdx.x;   // 131072 total
  int s = idx >> 6, j = idx & 63;
  double ang = (double)s * pow(10000.0, -(double)j / 64.0);
  tab[idx] = (float)cos(ang);
  tab[131072 + idx] = (float)sin(ang);
}

// ======== gemm_r3: C = A[M,K]*Bw[N,K]^T (bf16, K-major), BM=128 BN=256 BK=32 ========
// ring-3 LDS (72KB -> 2 blocks/CU), stage-ahead-2, 1 barrier + counted vmcnt(3)/K-tile,
// 16-MFMA setprio burst, T2 swizzle, 2D XCD chunking.
// EPI 0: fp32 row-major C.
// EPI 1: QKV epilogue — part 0/1 (q,k): RoPE fused (pair exchange via LDS across
//        wave w^1, cos/sin from tab, q scaled), scatter to qkv [part][b][h][s][d];
//        part 2 (v): write TRANSPOSED into vt[bh][d][s] (C2), 8B stores.
template<int EPI>
__global__ __launch_bounds__(512, 4) void gemm_r3(const u16* __restrict__ A, const u16* __restrict__ Bw,
                                                  void* __restrict__ C, void* __restrict__ C2,
                                                  const float* __restrict__ tab,
                                                  int M, int N, int K,
                                                  int xmBits, int cmMt, int cnNt) {
  __shared__ __align__(16) u16 shmem[36864];     // Al 12288 | Bl 24576 (73728 B)
  u16* Al = shmem;
  u16* Bl = shmem + 12288;
  const int t = threadIdx.x;
  const int w = t >> 6, l = t & 63;
  const int lr = l & 15, lg = l >> 4;
  const int wr = w >> 2, wc = w & 3;
  const int xcd = blockIdx.x & 7;
  const int loc = blockIdx.x >> 3;
  const int xm = xcd & ((1 << xmBits) - 1), xn = xcd >> xmBits;
  const int mt = xm * cmMt + (loc % cmMt);
  const int nt = xn * cnNt + (loc / cmMt);
  const int m0 = mt * 128, n0 = nt * 256;
  const int NT = K >> 5;

  const int pa = t * 16;
  const int oa = SWZ(pa);
  const u16* aSrc = A + (long)(m0 + (oa >> 6)) * K + ((oa & 63) >> 1);
  const int ob0 = SWZ(pa);
  const int ob1 = SWZ(8192 + pa);
  const u16* bSrc0 = Bw + (long)(n0 + (ob0 >> 6)) * K + ((ob0 & 63) >> 1);
  const u16* bSrc1 = Bw + (long)(n0 + ((ob1 - 8192) >> 6) + 128) * K + ((ob1 & 63) >> 1);
  const int ldsWave = w * 512;

  int aro[4], bro[4];
#pragma unroll
  for (int f = 0; f < 4; ++f) {
    int ab = (wr * 64 + f * 16 + lr) * 64 + lg * 16;
    aro[f] = SWZ(ab) >> 1;
    int bb = (wc * 64 + f * 16 + lr) * 64 + lg * 16;
    bro[f] = SWZ(bb) >> 1;
  }

  f32x4 acc[4][4];
#pragma unroll
  for (int i = 0; i < 4; ++i)
#pragma unroll
    for (int j = 0; j < 4; ++j)
#pragma unroll
      for (int e = 0; e < 4; ++e) acc[i][j][e] = 0.f;

#define STAGE(tt, sl)                                                     \
  do {                                                                    \
    gload_lds16(aSrc  + (tt) * 32, Al + (sl) * 4096 + ldsWave);           \
    gload_lds16(bSrc0 + (tt) * 32, Bl + (sl) * 8192 + ldsWave);           \
    gload_lds16(bSrc1 + (tt) * 32, Bl + (sl) * 8192 + 4096 + ldsWave);    \
  } while (0)

  STAGE(0, 0);
  STAGE(1, 1);
  asm volatile("s_waitcnt vmcnt(3)" ::: "memory");
  __builtin_amdgcn_s_barrier();

  int rs = 0, ss = 2;
  for (int tt = 0; tt < NT; ++tt) {
    const u16* as = Al + rs * 4096;
    const u16* bs = Bl + rs * 8192;
    bf16x8 b0 = *(const bf16x8*)(bs + bro[0]);
    bf16x8 b1 = *(const bf16x8*)(bs + bro[1]);
    bf16x8 b2 = *(const bf16x8*)(bs + bro[2]);
    bf16x8 b3 = *(const bf16x8*)(bs + bro[3]);
    bf16x8 a0 = *(const bf16x8*)(as + aro[0]);
    bf16x8 a1 = *(const bf16x8*)(as + aro[1]);
    bf16x8 a2 = *(const bf16x8*)(as + aro[2]);
    bf16x8 a3 = *(const bf16x8*)(as + aro[3]);
    if (tt + 2 < NT) STAGE(tt + 2, ss);
    __builtin_amdgcn_s_setprio(1);
    acc[0][0] = MFMA16(a0, b0, acc[0][0]);
    acc[0][1] = MFMA16(a0, b1, acc[0][1]);
    acc[0][2] = MFMA16(a0, b2, acc[0][2]);
    acc[0][3] = MFMA16(a0, b3, acc[0][3]);
    acc[1][0] = MFMA16(a1, b0, acc[1][0]);
    acc[1][1] = MFMA16(a1, b1, acc[1][1]);
    acc[1][2] = MFMA16(a1, b2, acc[1][2]);
    acc[1][3] = MFMA16(a1, b3, acc[1][3]);
    acc[2][0] = MFMA16(a2, b0, acc[2][0]);
    acc[2][1] = MFMA16(a2, b1, acc[2][1]);
    acc[2][2] = MFMA16(a2, b2, acc[2][2]);
    acc[2][3] = MFMA16(a2, b3, acc[2][3]);
    acc[3][0] = MFMA16(a3, b0, acc[3][0]);
    acc[3][1] = MFMA16(a3, b1, acc[3][1]);
    acc[3][2] = MFMA16(a3, b2, acc[3][2]);
    acc[3][3] = MFMA16(a3, b3, acc[3][3]);
    __builtin_amdgcn_s_setprio(0);
    asm volatile("s_waitcnt lgkmcnt(0)" ::: "memory");
    __builtin_amdgcn_sched_barrier(0);
    if (tt < NT - 2) asm volatile("s_waitcnt vmcnt(3)" ::: "memory");
    else             asm volatile("s_waitcnt vmcnt(0)" ::: "memory");
    __builtin_amdgcn_s_barrier();
    rs = (rs == 2) ? 0 : rs + 1;
    ss = (ss == 2) ? 0 : ss + 1;
  }
#undef STAGE

  if (EPI == 0) {
    float* Co = (float*)C;
#pragma unroll
    for (int mf = 0; mf < 4; ++mf)
#pragma unroll
      for (int nf = 0; nf < 4; ++nf)
#pragma unroll
        for (int j = 0; j < 4; ++j) {
          int row = m0 + wr * 64 + mf * 16 + lg * 4 + j;
          int col = n0 + wc * 64 + nf * 16 + lr;
          Co[(long)row * N + col] = acc[mf][nf][j];
        }
  } else {
    const int part = n0 >> 11;       // uniform per block (tile never crosses 2048)
    if (part < 2) {
      // ---- fused RoPE for q/k: pair exchange via LDS (wave w^1 <=> d^64) ----
#pragma unroll
      for (int mf = 0; mf < 4; ++mf)
#pragma unroll
        for (int nf = 0; nf < 4; ++nf) {
          ushort4 v;
          v.x = f2bf(acc[mf][nf][0]);
          v.y = f2bf(acc[mf][nf][1]);
          v.z = f2bf(acc[mf][nf][2]);
          v.w = f2bf(acc[mf][nf][3]);
          *(ushort4*)&shmem[((((w * 4 + mf) * 4 + nf) * 64) + l) * 4] = v;
        }
      __syncthreads();
      u16* Q = (u16*)C;
      const long PART = 8388608L;    // 2*16*2048*128
      const float scale = (part == 0) ? 0.12751744906275268f : 1.0f;  // 1/sqrt(128)*log2e
      const int dlow = (wc & 1) == 0;
#pragma unroll
      for (int mf = 0; mf < 4; ++mf)
#pragma unroll
        for (int nf = 0; nf < 4; ++nf) {
          ushort4 pv = *(const ushort4*)&shmem[(((((w ^ 1) * 4 + mf) * 4 + nf) * 64) + l) * 4];
#pragma unroll
          for (int j = 0; j < 4; ++j) {
            int row = m0 + wr * 64 + mf * 16 + lg * 4 + j;   // b*2048 + s
            int col = n0 + wc * 64 + nf * 16 + lr;
            int h = (col >> 7) & 15, d = col & 127;
            int b = row >> 11, s = row & 2047;
            int jj = d & 63;
            float cs = tab[s * 64 + jj];
            float sn = tab[131072 + s * 64 + jj];
            float own = acc[mf][nf][j];
            float oth = bf2f(((const u16*)&pv)[j]);
            float o = dlow ? (own * cs - oth * sn) : (own * cs + oth * sn);
            Q[part * PART + ((long)((b * 16 + h) * 2048 + s)) * 128 + d] = f2bf(o * scale);
          }
        }
    } else {
      // ---- v: write transposed into vt[bh][d][s]; j=0..3 are consecutive s ----
      u16* VT = (u16*)C2;
#pragma unroll
      for (int mf = 0; mf < 4; ++mf)
#pragma unroll
        for (int nf = 0; nf < 4; ++nf) {
          int row0 = m0 + wr * 64 + mf * 16 + lg * 4;        // j=0 row
          int col = n0 + wc * 64 + nf * 16 + lr;
          int h = (col >> 7) & 15, d = col & 127;
          int b = row0 >> 11, s0 = row0 & 2047;              // s0 multiple of 4
          ushort4 v;
          v.x = f2bf(acc[mf][nf][0]);
          v.y = f2bf(acc[mf][nf][1]);
          v.z = f2bf(acc[mf][nf][2]);
          v.w = f2bf(acc[mf][nf][3]);
          *(ushort4*)&VT[(long)(b * 16 + h) * 262144 + (long)d * 2048 + s0] = v;
        }
    }
  }
}

// ---------------- Flash attention (causal), QB=KB=64, 4 waves, swizzled K/V LDS ----
// R20 structure + conditional max-reduce: the 4-level shfl max tree runs ONLY when
// the defer-max skip check fails. Skip check on LANE-PARTIAL pmax via __all is
// semantically identical (mrow is group-uniform; __all(partial<=thr) <=> groupmax<=thr).
// Common path per step: 3 fmax + __all, no shfl. Sum reduce stays deferred (R20).
__global__ __launch_bounds__(256, 3) void flash_fwd(const u16* __restrict__ qg, const u16* __restrict__ kg,
                                                    const u16* __restrict__ vtg, u16* __restrict__ ctx) {
  const int bid = blockIdx.x;
  const int xcd = bid & 7;
  const int seq = bid >> 3;
  const int bh = xcd * 4 + (seq & 3);
  const int qi = 31 - (seq >> 2);
  const int t = threadIdx.x, w = t >> 6, l = t & 63;
  const int lr = l & 15, lg = l >> 4;
  const int q0 = qi * 64;
  const int nkv = qi + 1;
  const long skbase = (long)bh * 2048 * 128;
  const long vtbase = (long)bh * 128 * 2048;
  __shared__ __align__(16) u16 Kl[64 * 128];   // 16 KB, swizzled
  __shared__ __align__(16) u16 Vl[128 * 64];   // 16 KB, swizzled
  __shared__ __align__(16) u16 Pl[4][16][72];  // per-wave P [q][kv], padded rows

  bf16x8 qf[4];
  {
    const u16* qrow = qg + skbase + (long)(q0 + w * 16 + lr) * 128;
#pragma unroll
    for (int dc = 0; dc < 4; ++dc) qf[dc] = *(const bf16x8*)(qrow + dc * 32 + lg * 8);
  }
  f32x4 acc[8];
#pragma unroll
  for (int dc = 0; dc < 8; ++dc)
#pragma unroll
    for (int e = 0; e < 4; ++e) acc[dc][e] = 0.f;
  float mrow[4] = {-1e30f, -1e30f, -1e30f, -1e30f};
  float lsum[4] = {0.f, 0.f, 0.f, 0.f};        // LANE-PARTIAL row sums

  const u16* kga = kg + skbase + (long)(t >> 4) * 128 + (t & 15) * 8;
  const u16* vga = vtg + vtbase + (long)(t >> 3) * 2048 + (t & 7) * 8;
  const int kWrO = (t >> 4) * 256 + (((t & 15) * 16) ^ (((t >> 4) & 7) << 4));
  const int vWrO = (t >> 3) * 128 + (((t & 7) * 16) ^ (((t >> 3) & 7) << 4));
  const int msk = (lr & 7) << 4;
  char* KlB = (char*)Kl;
  char* VlB = (char*)Vl;

  u16x8 rk[4], rv[4];
#pragma unroll
  for (int it = 0; it < 4; ++it) {
    rk[it] = *(const u16x8*)(kga + it * 2048);
    rv[it] = *(const u16x8*)(vga + it * 65536);
  }

  for (int kvt = 0; kvt < nkv; ++kvt) {
    __syncthreads();
#pragma unroll
    for (int it = 0; it < 4; ++it) {
      *(u16x8*)(KlB + kWrO + it * 4096) = rk[it];
      *(u16x8*)(VlB + vWrO + it * 4096) = rv[it];
    }
    __syncthreads();
    if (kvt + 1 < nkv) {
      const u16* ka = kga + (long)(kvt + 1) * 8192;
      const u16* va = vga + (long)(kvt + 1) * 64;
#pragma unroll
      for (int it = 0; it < 4; ++it) {
        rk[it] = *(const u16x8*)(ka + it * 2048);
        rv[it] = *(const u16x8*)(va + it * 65536);
      }
    }

    const int kv0 = kvt * 64;
    f32x4 sc[4];
#pragma unroll
    for (int c = 0; c < 4; ++c)
#pragma unroll
      for (int e = 0; e < 4; ++e) sc[c][e] = 0.f;
    __builtin_amdgcn_s_setprio(1);
#pragma unroll
    for (int dc = 0; dc < 4; ++dc)
#pragma unroll
      for (int c = 0; c < 4; ++c) {
        bf16x8 kf = *(const bf16x8*)(KlB + c * 4096 + lr * 256 + ((dc * 64 + lg * 16) ^ msk));
        sc[c] = MFMA16(qf[dc], kf, sc[c]);
      }
    __builtin_amdgcn_s_setprio(0);

    if (kvt == qi) {
#pragma unroll
      for (int c = 0; c < 4; ++c)
#pragma unroll
        for (int j = 0; j < 4; ++j) {
          int kvi = kv0 + c * 16 + lr;
          int qq = q0 + w * 16 + lg * 4 + j;
          if (kvi > qq) sc[c][j] = -1e30f;
        }
    }

    // lane-partial max (no shfl)
    float pmax[4];
#pragma unroll
    for (int j = 0; j < 4; ++j)
      pmax[j] = fmaxf(fmaxf(sc[0][j], sc[1][j]), fmaxf(sc[2][j], sc[3][j]));

    // skip check on partial pmax: equivalent to check on reduced pmax
    int skip = __all(pmax[0] <= mrow[0] + 8.f && pmax[1] <= mrow[1] + 8.f &&
                     pmax[2] <= mrow[2] + 8.f && pmax[3] <= mrow[3] + 8.f);
    if (!skip) {
      // full max reduce only when rescale is needed
#pragma unroll
      for (int off = 8; off >= 1; off >>= 1)
#pragma unroll
        for (int j = 0; j < 4; ++j)
          pmax[j] = fmaxf(pmax[j], __shfl_xor(pmax[j], off));
#pragma unroll
      for (int j = 0; j < 4; ++j) {
        float mn = fmaxf(mrow[j], pmax[j]);
        float alpha = __builtin_amdgcn_exp2f(mrow[j] - mn);
        mrow[j] = mn;
        lsum[j] *= alpha;
#pragma unroll
        for (int dc = 0; dc < 8; ++dc) acc[dc][j] *= alpha;
      }
    }

#pragma unroll
    for (int c = 0; c < 4; ++c)
#pragma unroll
      for (int j = 0; j < 4; ++j) {
        float p = __builtin_amdgcn_exp2f(sc[c][j] - mrow[j]);
        sc[c][j] = p;
        lsum[j] += p;                 // lane-partial; reduced once after the loop
      }

#pragma unroll
    for (int c = 0; c < 4; ++c)
#pragma unroll
      for (int j = 0; j < 4; ++j)
        Pl[w][lg * 4 + j][c * 16 + lr] = f2bf(sc[c][j]);

    __builtin_amdgcn_s_setprio(1);
#pragma unroll
    for (int kc = 0; kc < 2; ++kc) {
      bf16x8 pa = *(const bf16x8*)&Pl[w][lr][kc * 32 + lg * 8];
#pragma unroll
      for (int dc = 0; dc < 8; ++dc) {
        bf16x8 vb = *(const bf16x8*)(VlB + dc * 2048 + lr * 128 + ((kc * 64 + lg * 16) ^ msk));
        acc[dc] = MFMA16(pa, vb, acc[dc]);
      }
    }
    __builtin_amdgcn_s_setprio(0);
  }

  // final cross-lane sum reduce (once)
#pragma unroll
  for (int off = 8; off >= 1; off >>= 1)
#pragma unroll
    for (int j = 0; j < 4; ++j)
      lsum[j] += __shfl_xor(lsum[j], off);

  const int b = bh >> 4, h = bh & 15;
#pragma unroll
  for (int j = 0; j < 4; ++j) {
    float inv = 1.f / lsum[j];
    int s = q0 + w * 16 + lg * 4 + j;
    u16* orow = ctx + ((long)(b * 2048 + s)) * 2048 + h * 128;
#pragma unroll
    for (int dc = 0; dc < 8; ++dc)
      orow[dc * 16 + lr] = f2bf(acc[dc][j] * inv);
  }
}

// ---------------- launch ----------------
extern "C" void kernel_launch(void* const* d_in, const int* in_sizes, int n_in,
                              void* d_out, int out_size, void* d_ws, size_t ws_size,
                              hipStream_t stream) {
  const float* x = (const float*)d_in[0];
  const float* wqkv = (const float*)d_in[1];
  const float* wproj = (const float*)d_in[2];
  float* out = (float*)d_out;

  u16* xb   = (u16*)d_ws;             // 8,388,608 elems
  u16* wqb  = xb + 8388608;           // 12,582,912
  u16* wpb  = wqb + 12582912;         // 4,194,304
  u16* qkv  = wpb + 4194304;          // 25,165,824 (q | k; v slot unused)
  u16* vt   = qkv + 25165824;         // 8,388,608
  u16* ctx  = vt + 8388608;           // 8,388,608
  float* tab = (float*)(ctx + 8388608); // 262,144 floats

  cast3<<<4096, 256, 0, stream>>>(x, wqkv, wproj, xb, wqb, wpb);
  rope_table<<<512, 256, 0, stream>>>(tab);

  // QKV projection + fused RoPE(q,k) + fused V-transpose. 768 blocks; XCD chunk 16x6.
  gemm_r3<1><<<768, 512, 0, stream>>>(xb, wqb, qkv, vt, tab, 4096, 6144, 2048, 1, 16, 6);

  // Flash: QB=64, 1024 blocks, 256 threads, deferred sum + conditional max reduce
  flash_fwd<<<1024, 256, 0, stream>>>(qkv, qkv + 8388608, vt, ctx);

  // Output projection -> fp32 d_out. 256 blocks; XCD chunk 8x4.
  gemm_r3<0><<<256, 512, 0, stream>>>(ctx, wpb, out, nullptr, nullptr, 4096, 2048, 2048, 2, 8, 4);
}